// Round 16
// baseline (1354.311 us; speedup 1.0000x reference)
//
#include <hip/hip_runtime.h>
#include <hip/hip_bf16.h>

// SwinMLP block, fp32 in/out, bf16 MFMA internals.
// R16: SHAPE-MATCHED GEMM STRUCTURE (tall-skinny M=100K):
//   B-panel LDS-resident (staged once per 512-K chunk), A streamed
//   global->VGPR in MFMA-fragment-PACKED layout (all intermediates are
//   ours: ybuf, zbuf, w1p, w2p all packed). K-loop has ZERO barriers.
//   Packed format: P[g=row>>4][t=k>>5][l=(row&15)+16*((k>>3)&3)][j=k&7],
//   1KB blocks; A-frag load = contiguous (g*NKT+t)*1024 + lane*16 (coalesced,
//   unlike R10's 16-line gather). B-frag ds_read lane-linear: conflict-free.
//   Block 128M x 64N, 4 waves x (32M x 64N), acc[2][4] (32 AGPR).
//   gemm1 (K=512): stage 64KB once; 16 steps; GELU epilogue -> packed z
//   (16KB LDS bounce). gemm2 (K=2048): 4 chunks x {stage 64KB, 16 steps};
//   residual RMW epilogue (32KB f32 bounce reusing B region).
// Evidence: R1-R15 all schedule/occupancy levers null at ~24% MfmaUtil;
// wall = lockstep burst chain. This removes the mechanism.

typedef __bf16 bf16x8 __attribute__((ext_vector_type(8)));
typedef float f32x4 __attribute__((ext_vector_type(4)));

constexpr int CDIM = 512;
constexpr int HID = 2048;
constexpr int MROWS = 32 * 3136;  // 100352 = 784 * 128
constexpr float LN_EPS = 1e-5f;

static __device__ __forceinline__ float gelu_tanh(float x) {
  const float u = 0.7978845608028654f * fmaf(0.044715f * x * x, x, x);
  const float e = __expf(2.0f * u);
  return 0.5f * x * (2.0f - 2.0f / (e + 1.0f));
}

static __device__ __forceinline__ void load_lds16(const void* g, void* l) {
  __builtin_amdgcn_global_load_lds((__attribute__((address_space(1))) void*)g,
                                   (__attribute__((address_space(3))) void*)l,
                                   16, 0, 0);
}

// ---- pack fp32 w[KD][ND] -> bf16 packed fragments (rows = ND dim) ----
// P block o = (g*NKT + t)*64 + l (16B each): n = g*16+(l&15),
// k = t*32 + (l>>4)*8 + j, j = 0..7.
template <int KD, int ND>
__global__ __launch_bounds__(256) void cvt_pack(const float* __restrict__ src,
                                                __hip_bfloat16* __restrict__ dst) {
  constexpr int NKT = KD / 32;
  const int o = blockIdx.x * 256 + threadIdx.x;
  const int l = o & 63;
  const int gt = o >> 6;
  const int t = gt & (NKT - 1), g = gt / NKT;
  const int n = g * 16 + (l & 15);
  const int k0 = t * 32 + (l >> 4) * 8;
  __hip_bfloat16 v[8];
#pragma unroll
  for (int j = 0; j < 8; ++j)
    v[j] = __float2bfloat16(src[(size_t)(k0 + j) * ND + n]);
  *(uint4*)(dst + (size_t)o * 8) = *(const uint4*)v;
}

// -------- fused LN1 + spatial mix + residual + LN2 (y out PACKED) ----------
__global__ __launch_bounds__(256) void fused_pre(
    const float* __restrict__ x, const float* __restrict__ g1,
    const float* __restrict__ b1, const float* __restrict__ wsp,
    const float* __restrict__ g2, const float* __restrict__ b2,
    float* __restrict__ x2out, __hip_bfloat16* __restrict__ yout) {
  __shared__ float lnbuf[2][CDIM];
  __shared__ float red[16];

  const int t = threadIdx.x;
  const int lane = t & 63;
  const int w = t >> 6;
  const int c0 = 2 * t;
  const int hd = c0 >> 5, e0 = c0 & 31;
  // packed y offset (elems), constant part: t-block + kg + j
  const int ypc = (c0 >> 5) * 512 + ((c0 >> 3) & 3) * 128 + (c0 & 7);

  float wc0[32], wc1[32];
#pragma unroll
  for (int d = 0; d < 32; ++d) {
    const float2 wv = *(const float2*)&wsp[(hd * 32 + d) * 32 + e0];
    wc0[d] = wv.x;
    wc1[d] = wv.y;
  }
  const float2 g1v = *(const float2*)&g1[c0];
  const float2 b1v = *(const float2*)&b1[c0];
  const float2 g2v = *(const float2*)&g2[c0];
  const float2 b2v = *(const float2*)&b2[c0];

  for (int rp = blockIdx.x; rp < MROWS / 2; rp += gridDim.x) {
    const size_t ra = (size_t)rp * 2, rb = ra + 1;
    const float2 xa = *(const float2*)&x[ra * CDIM + c0];
    const float2 xb = *(const float2*)&x[rb * CDIM + c0];

    float sa = xa.x + xa.y, qa = xa.x * xa.x + xa.y * xa.y;
    float sb = xb.x + xb.y, qb = xb.x * xb.x + xb.y * xb.y;
#pragma unroll
    for (int off = 32; off; off >>= 1) {
      sa += __shfl_down(sa, off);
      qa += __shfl_down(qa, off);
      sb += __shfl_down(sb, off);
      qb += __shfl_down(qb, off);
    }
    if (lane == 0) {
      red[w * 4 + 0] = sa;
      red[w * 4 + 1] = qa;
      red[w * 4 + 2] = sb;
      red[w * 4 + 3] = qb;
    }
    __syncthreads();
    sa = red[0] + red[4] + red[8] + red[12];
    qa = red[1] + red[5] + red[9] + red[13];
    sb = red[2] + red[6] + red[10] + red[14];
    qb = red[3] + red[7] + red[11] + red[15];
    float mua = sa * (1.0f / CDIM), mub = sb * (1.0f / CDIM);
    float rsa = rsqrtf(qa * (1.0f / CDIM) - mua * mua + LN_EPS);
    float rsb = rsqrtf(qb * (1.0f / CDIM) - mub * mub + LN_EPS);
    lnbuf[0][c0] = (xa.x - mua) * rsa * g1v.x + b1v.x;
    lnbuf[0][c0 + 1] = (xa.y - mua) * rsa * g1v.y + b1v.y;
    lnbuf[1][c0] = (xb.x - mub) * rsb * g1v.x + b1v.x;
    lnbuf[1][c0 + 1] = (xb.y - mub) * rsb * g1v.y + b1v.y;
    __syncthreads();

    float ha0 = 0.f, ha1 = 0.f, hb0 = 0.f, hb1 = 0.f;
#pragma unroll
    for (int d = 0; d < 32; ++d) {
      const float la = lnbuf[0][hd * 32 + d];
      const float lb = lnbuf[1][hd * 32 + d];
      ha0 = fmaf(la, wc0[d], ha0);
      ha1 = fmaf(la, wc1[d], ha1);
      hb0 = fmaf(lb, wc0[d], hb0);
      hb1 = fmaf(lb, wc1[d], hb1);
    }
    const float a0 = xa.x + ha0, a1 = xa.y + ha1;
    const float b0 = xb.x + hb0, b1r = xb.y + hb1;
    float2 av;
    av.x = a0;
    av.y = a1;
    *(float2*)&x2out[ra * CDIM + c0] = av;
    av.x = b0;
    av.y = b1r;
    *(float2*)&x2out[rb * CDIM + c0] = av;

    sa = a0 + a1;
    qa = a0 * a0 + a1 * a1;
    sb = b0 + b1r;
    qb = b0 * b0 + b1r * b1r;
#pragma unroll
    for (int off = 32; off; off >>= 1) {
      sa += __shfl_down(sa, off);
      qa += __shfl_down(qa, off);
      sb += __shfl_down(sb, off);
      qb += __shfl_down(qb, off);
    }
    if (lane == 0) {
      red[w * 4 + 0] = sa;
      red[w * 4 + 1] = qa;
      red[w * 4 + 2] = sb;
      red[w * 4 + 3] = qb;
    }
    __syncthreads();
    sa = red[0] + red[4] + red[8] + red[12];
    qa = red[1] + red[5] + red[9] + red[13];
    sb = red[2] + red[6] + red[10] + red[14];
    qb = red[3] + red[7] + red[11] + red[15];
    mua = sa * (1.0f / CDIM);
    mub = sb * (1.0f / CDIM);
    rsa = rsqrtf(qa * (1.0f / CDIM) - mua * mua + LN_EPS);
    rsb = rsqrtf(qb * (1.0f / CDIM) - mub * mub + LN_EPS);
    __hip_bfloat162 yv;
    // packed writes: elem off = (r>>4)*8192 + (r&15)*8 + ypc (j,j+1 contig)
    yv.x = __float2bfloat16((a0 - mua) * rsa * g2v.x + b2v.x);
    yv.y = __float2bfloat16((a1 - mua) * rsa * g2v.y + b2v.y);
    *(__hip_bfloat162*)&yout[(ra >> 4) * 8192 + (ra & 15) * 8 + ypc] = yv;
    yv.x = __float2bfloat16((b0 - mub) * rsb * g2v.x + b2v.x);
    yv.y = __float2bfloat16((b1r - mub) * rsb * g2v.y + b2v.y);
    *(__hip_bfloat162*)&yout[(rb >> 4) * 8192 + (rb & 15) * 8 + ypc] = yv;
    __syncthreads();
  }
}

// ---- streaming GEMM: A packed (global->VGPR), B packed (LDS-resident) ----
// NKT = K/32 total; NCH chunks of 16 kt (512 k) each; NP = N/64 panels.
// Block: 128M x 64N; 4 waves x (32M x 64N); acc[2][4].
// GELU: z output PACKED (NKT2=64) via 16KB LDS bounce at offset 65536.
// else: fout += acc + bias (row-major N=512) via 32KB f32 bounce at 0.
template <int NKT, int NCH, int NP, bool GELU>
__global__ __launch_bounds__(256, 2) void gemmst(
    const char* __restrict__ Ap, const char* __restrict__ Bp,
    const float* __restrict__ bias, char* __restrict__ zp,
    float* __restrict__ fout) {
  constexpr int LDSZ = GELU ? 81920 : 65536;
  __shared__ __attribute__((aligned(16))) char smem[LDSZ];

  const int tid = threadIdx.x;
  const int lane = tid & 63;
  const int w = tid >> 6;  // wave 0..3 owns rows w*32..w*32+31

  // T1 swizzle; bid = mt*NP + np (consecutive bids share A m-tile -> L2)
  const int cpx = gridDim.x >> 3;
  const int bid = (blockIdx.x & 7) * cpx + (blockIdx.x >> 3);
  const int mt = bid / NP, np = bid % NP;

  f32x4 acc[2][4] = {};

  for (int c = 0; c < NCH; ++c) {
    // ---- stage B chunk: 4 n-groups x 16KB (lane-linear, coalesced) ----
    if (c) __syncthreads();  // seal previous chunk's reads
#pragma unroll
    for (int i = 0; i < 16; ++i) {
      const int g = i >> 2, sub = i & 3;
      const int loff = g * 16384 + sub * 4096 + w * 1024 + lane * 16;
      load_lds16(Bp + ((size_t)(np * 4 + g) * NKT + c * 16) * 1024 +
                     sub * 4096 + w * 1024 + lane * 16,
                 smem + loff);
    }
    __syncthreads();  // drains vmcnt(0); B chunk resident

    // ---- K-loop: NO barriers; A streams global->VGPR (packed, coalesced) --
#pragma unroll 4
    for (int ktl = 0; ktl < 16; ++ktl) {
      const int t = c * 16 + ktl;
      bf16x8 af[2], bf[4];
#pragma unroll
      for (int mi = 0; mi < 2; ++mi)
        af[mi] = *(const bf16x8*)(Ap +
                                  (((size_t)(mt * 8 + w * 2 + mi)) * NKT + t) *
                                      1024 +
                                  lane * 16);
#pragma unroll
      for (int n = 0; n < 4; ++n)
        bf[n] = *(const bf16x8*)(smem + (n * 16 + ktl) * 1024 + lane * 16);
#pragma unroll
      for (int mi = 0; mi < 2; ++mi)
#pragma unroll
        for (int n = 0; n < 4; ++n)
          acc[mi][n] = __builtin_amdgcn_mfma_f32_16x16x32_bf16(
              af[mi], bf[n], acc[mi][n], 0, 0, 0);
    }
  }

  // ---- epilogue ----
  // C/D map: col16 = lane&15, row16 = (lane>>4)*4 + j  [m89/m91-verified]
  float bv[4];
#pragma unroll
  for (int n = 0; n < 4; ++n) bv[n] = bias[np * 64 + n * 16 + (lane & 15)];

  if constexpr (GELU) {
    // pack z for gemm2-A (NKT2 = 64): bounce 16KB at offset 65536
    __syncthreads();  // B region untouched; sync for bounce-region reuse
#pragma unroll
    for (int mi = 0; mi < 2; ++mi)
#pragma unroll
      for (int n = 0; n < 4; ++n)
#pragma unroll
        for (int j = 0; j < 4; ++j) {
          const float v = gelu_tanh(acc[mi][n][j] + bv[n]);
          const int l2 = ((lane >> 4) * 4 + j) +
                         16 * ((n * 2 + ((lane & 15) >> 3)) & 3);
          const int blk = (w * 2 + mi) * 2 + (n >> 1);
          *(__hip_bfloat16*)(smem + 65536 + blk * 1024 + l2 * 16 +
                             (lane & 7) * 2) = __float2bfloat16(v);
        }
    __syncthreads();
#pragma unroll
    for (int p = 0; p < 4; ++p) {
      const int blk = p * 4 + (tid >> 6);
      const size_t gdst =
          (((size_t)(mt * 8 + (blk >> 1))) * 64 + np * 2 + (blk & 1)) << 10;
      *(uint4*)(zp + gdst + lane * 16) =
          *(const uint4*)(smem + 65536 + blk * 1024 + lane * 16);
    }
  } else {
    // residual RMW: bounce 128x64 f32 (32KB) reusing B region
    __syncthreads();  // all waves done reading B
#pragma unroll
    for (int mi = 0; mi < 2; ++mi)
#pragma unroll
      for (int n = 0; n < 4; ++n)
#pragma unroll
        for (int j = 0; j < 4; ++j) {
          const int row = w * 32 + mi * 16 + (lane >> 4) * 4 + j;
          const int col = n * 16 + (lane & 15);
          *(float*)(smem + (row * 64 + col) * 4) = acc[mi][n][j] + bv[n];
        }
    __syncthreads();
#pragma unroll
    for (int p = 0; p < 8; ++p) {
      const int s = p * 256 + tid;  // 2048 x 16B
      const int row = s >> 4, c4 = s & 15;
      const float4 lv = *(const float4*)(smem + s * 16);
      float* gp = &fout[((size_t)(mt * 128 + row)) * 512 + np * 64 + c4 * 4];
      float4 o = *(const float4*)gp;
      o.x += lv.x;
      o.y += lv.y;
      o.z += lv.z;
      o.w += lv.w;
      *(float4*)gp = o;
    }
  }
}

extern "C" void kernel_launch(void* const* d_in, const int* in_sizes, int n_in,
                              void* d_out, int out_size, void* d_ws,
                              size_t ws_size, hipStream_t stream) {
  const float* x = (const float*)d_in[0];
  const float* n1g = (const float*)d_in[1];
  const float* n1b = (const float*)d_in[2];
  const float* wsp = (const float*)d_in[3];
  const float* n2g = (const float*)d_in[4];
  const float* n2b = (const float*)d_in[5];
  const float* w1 = (const float*)d_in[6];
  const float* b1 = (const float*)d_in[7];
  const float* w2 = (const float*)d_in[8];
  const float* b2 = (const float*)d_in[9];
  float* out = (float*)d_out;

  // ws (bf16): y_packed[M*512] | z_packed[M*2048] | w1p[2048*512] | w2p[512*2048]
  __hip_bfloat16* ybuf = (__hip_bfloat16*)d_ws;
  __hip_bfloat16* zbuf = ybuf + (size_t)MROWS * CDIM;
  __hip_bfloat16* w1p = zbuf + (size_t)MROWS * HID;
  __hip_bfloat16* w2p = w1p + (size_t)CDIM * HID;

  cvt_pack<CDIM, HID><<<512, 256, 0, stream>>>(w1, w1p);   // w1[512][2048]
  cvt_pack<HID, CDIM><<<512, 256, 0, stream>>>(w2, w2p);   // w2[2048][512]
  fused_pre<<<2048, 256, 0, stream>>>(x, n1g, n1b, wsp, n2g, n2b, out, ybuf);
  // gemm1: K=512 (NKT=16, 1 chunk), N=2048 (32 panels): grid 784*32 % 8 == 0
  gemmst<16, 1, 32, true><<<784 * 32, 256, 0, stream>>>(
      (const char*)ybuf, (const char*)w1p, b1, (char*)zbuf, nullptr);
  // gemm2: K=2048 (NKT=64, 4 chunks), N=512 (8 panels): grid 784*8 % 8 == 0
  gemmst<64, 4, 8, false><<<784 * 8, 256, 0, stream>>>(
      (const char*)zbuf, (const char*)w2p, b2, nullptr, out);
}

// Round 17
// 880.603 us; speedup vs baseline: 1.5379x; 1.5379x over previous
//
#include <hip/hip_runtime.h>
#include <hip/hip_bf16.h>

// SwinMLP block, fp32 in/out, bf16 MFMA internals.
//   1) cvt_pack: w1/w2 -> MFMA-fragment-packed bf16 (R16-proven format)
//   2) fused_pre: LN1 + spatial mix + residual -> x2 (d_out); LN2 -> y (row-major bf16)
//   3) gemmbs<512,2048,GELU>: z = gelu(y @ w1 + b1)   (z row-major bf16)
//   4) gemmbs<2048,512,RES>:  d_out = x2 + z @ w2 + b2
//
// Model after R16: LDS bandwidth is the wall. R12/R15 (both operands staged)
// move 48KB LDS per 1.05 MFLOP block-step -> bound ~36-42% MfmaUtil; all such
// variants measure 22-24%. R16 (A global) starved MFMA (13.8%) - global
// operand on critical path. R17 (this): HYBRID - A staged in LDS (R15 dbuf,
// passed), B streamed global->VGPR in packed format (R16-proven, L2-hot
// weights, 2-wave L1 broadcast) with next-step prefetch drained by the same
// __syncthreads that seals the A-stage. LDS traffic 48->24KB per block-step.

typedef __bf16 bf16x8 __attribute__((ext_vector_type(8)));
typedef float f32x4 __attribute__((ext_vector_type(4)));

constexpr int CDIM = 512;
constexpr int HID = 2048;
constexpr int MROWS = 32 * 3136;  // 100352 = 784 * 128
constexpr float LN_EPS = 1e-5f;

static __device__ __forceinline__ float gelu_tanh(float x) {
  const float u = 0.7978845608028654f * fmaf(0.044715f * x * x, x, x);
  const float e = __expf(2.0f * u);
  return 0.5f * x * (2.0f - 2.0f / (e + 1.0f));
}

static __device__ __forceinline__ void load_lds16(const void* g, void* l) {
  // 16B/lane; LDS dest = wave-uniform base + lane*16 (linear)
  __builtin_amdgcn_global_load_lds((__attribute__((address_space(1))) void*)g,
                                   (__attribute__((address_space(3))) void*)l,
                                   16, 0, 0);
}

// ---- pack fp32 w[KD][ND] -> bf16 packed fragments (R16-proven) ----
// Block o = (g*NKT + t)*64 + l (16B): n = g*16+(l&15), k = t*32+(l>>4)*8+j.
template <int KD, int ND>
__global__ __launch_bounds__(256) void cvt_pack(const float* __restrict__ src,
                                                __hip_bfloat16* __restrict__ dst) {
  constexpr int NKT = KD / 32;
  const int o = blockIdx.x * 256 + threadIdx.x;
  const int l = o & 63;
  const int gt = o >> 6;
  const int t = gt & (NKT - 1), g = gt / NKT;
  const int n = g * 16 + (l & 15);
  const int k0 = t * 32 + (l >> 4) * 8;
  __hip_bfloat16 v[8];
#pragma unroll
  for (int j = 0; j < 8; ++j)
    v[j] = __float2bfloat16(src[(size_t)(k0 + j) * ND + n]);
  *(uint4*)(dst + (size_t)o * 8) = *(const uint4*)v;
}

// -------- fused LN1 + spatial mix + residual + LN2, 2 rows / iteration ------
__global__ __launch_bounds__(256) void fused_pre(
    const float* __restrict__ x, const float* __restrict__ g1,
    const float* __restrict__ b1, const float* __restrict__ wsp,
    const float* __restrict__ g2, const float* __restrict__ b2,
    float* __restrict__ x2out, __hip_bfloat16* __restrict__ yout) {
  __shared__ float lnbuf[2][CDIM];
  __shared__ float red[16];

  const int t = threadIdx.x;
  const int lane = t & 63;
  const int w = t >> 6;
  const int c0 = 2 * t;
  const int hd = c0 >> 5, e0 = c0 & 31;

  float wc0[32], wc1[32];
#pragma unroll
  for (int d = 0; d < 32; ++d) {
    const float2 wv = *(const float2*)&wsp[(hd * 32 + d) * 32 + e0];
    wc0[d] = wv.x;
    wc1[d] = wv.y;
  }
  const float2 g1v = *(const float2*)&g1[c0];
  const float2 b1v = *(const float2*)&b1[c0];
  const float2 g2v = *(const float2*)&g2[c0];
  const float2 b2v = *(const float2*)&b2[c0];

  for (int rp = blockIdx.x; rp < MROWS / 2; rp += gridDim.x) {
    const size_t ra = (size_t)rp * 2, rb = ra + 1;
    const float2 xa = *(const float2*)&x[ra * CDIM + c0];
    const float2 xb = *(const float2*)&x[rb * CDIM + c0];

    float sa = xa.x + xa.y, qa = xa.x * xa.x + xa.y * xa.y;
    float sb = xb.x + xb.y, qb = xb.x * xb.x + xb.y * xb.y;
#pragma unroll
    for (int off = 32; off; off >>= 1) {
      sa += __shfl_down(sa, off);
      qa += __shfl_down(qa, off);
      sb += __shfl_down(sb, off);
      qb += __shfl_down(qb, off);
    }
    if (lane == 0) {
      red[w * 4 + 0] = sa;
      red[w * 4 + 1] = qa;
      red[w * 4 + 2] = sb;
      red[w * 4 + 3] = qb;
    }
    __syncthreads();  // B1
    sa = red[0] + red[4] + red[8] + red[12];
    qa = red[1] + red[5] + red[9] + red[13];
    sb = red[2] + red[6] + red[10] + red[14];
    qb = red[3] + red[7] + red[11] + red[15];
    float mua = sa * (1.0f / CDIM), mub = sb * (1.0f / CDIM);
    float rsa = rsqrtf(qa * (1.0f / CDIM) - mua * mua + LN_EPS);
    float rsb = rsqrtf(qb * (1.0f / CDIM) - mub * mub + LN_EPS);
    lnbuf[0][c0] = (xa.x - mua) * rsa * g1v.x + b1v.x;
    lnbuf[0][c0 + 1] = (xa.y - mua) * rsa * g1v.y + b1v.y;
    lnbuf[1][c0] = (xb.x - mub) * rsb * g1v.x + b1v.x;
    lnbuf[1][c0 + 1] = (xb.y - mub) * rsb * g1v.y + b1v.y;
    __syncthreads();  // B2

    float ha0 = 0.f, ha1 = 0.f, hb0 = 0.f, hb1 = 0.f;
#pragma unroll
    for (int d = 0; d < 32; ++d) {
      const float la = lnbuf[0][hd * 32 + d];
      const float lb = lnbuf[1][hd * 32 + d];
      ha0 = fmaf(la, wc0[d], ha0);
      ha1 = fmaf(la, wc1[d], ha1);
      hb0 = fmaf(lb, wc0[d], hb0);
      hb1 = fmaf(lb, wc1[d], hb1);
    }
    const float a0 = xa.x + ha0, a1 = xa.y + ha1;
    const float b0 = xb.x + hb0, b1r = xb.y + hb1;
    float2 av;
    av.x = a0;
    av.y = a1;
    *(float2*)&x2out[ra * CDIM + c0] = av;
    av.x = b0;
    av.y = b1r;
    *(float2*)&x2out[rb * CDIM + c0] = av;

    sa = a0 + a1;
    qa = a0 * a0 + a1 * a1;
    sb = b0 + b1r;
    qb = b0 * b0 + b1r * b1r;
#pragma unroll
    for (int off = 32; off; off >>= 1) {
      sa += __shfl_down(sa, off);
      qa += __shfl_down(qa, off);
      sb += __shfl_down(sb, off);
      qb += __shfl_down(qb, off);
    }
    if (lane == 0) {
      red[w * 4 + 0] = sa;
      red[w * 4 + 1] = qa;
      red[w * 4 + 2] = sb;
      red[w * 4 + 3] = qb;
    }
    __syncthreads();  // B3
    sa = red[0] + red[4] + red[8] + red[12];
    qa = red[1] + red[5] + red[9] + red[13];
    sb = red[2] + red[6] + red[10] + red[14];
    qb = red[3] + red[7] + red[11] + red[15];
    mua = sa * (1.0f / CDIM);
    mub = sb * (1.0f / CDIM);
    rsa = rsqrtf(qa * (1.0f / CDIM) - mua * mua + LN_EPS);
    rsb = rsqrtf(qb * (1.0f / CDIM) - mub * mub + LN_EPS);
    __hip_bfloat162 yv;
    yv.x = __float2bfloat16((a0 - mua) * rsa * g2v.x + b2v.x);
    yv.y = __float2bfloat16((a1 - mua) * rsa * g2v.y + b2v.y);
    *(__hip_bfloat162*)&yout[ra * CDIM + c0] = yv;
    yv.x = __float2bfloat16((b0 - mub) * rsb * g2v.x + b2v.x);
    yv.y = __float2bfloat16((b1r - mub) * rsb * g2v.y + b2v.y);
    *(__hip_bfloat162*)&yout[rb * CDIM + c0] = yv;
    __syncthreads();  // B4
  }
}

// ---- 128x128 tile, 4 waves, BK=32: A LDS-dbuf (R15), B global-streamed ----
// C(MxN) = A(MxK) * Bpacked.  LDS = 2 A-slots x 8KB (+ 32KB epilogue bounce).
// Per tile t (slot d=t&1): STAGE_A(t+1 -> d^1) and B-prefetch bfn(t+1) issue
// FIRST; ds_read A(t) + 16 MFMA with bf(t); __syncthreads (drains stage AND
// bfn -> both covered by this step's compute). B is L2/L1-hot (784-block
// reuse; 2 waves per block duplicate each read -> L1 broadcast).
template <int K, int N, bool GELU>
__global__ __launch_bounds__(256, 3) void gemmbs(
    const __hip_bfloat16* __restrict__ A, const char* __restrict__ Bp,
    const float* __restrict__ bias, __hip_bfloat16* __restrict__ zout,
    float* __restrict__ fout) {
  constexpr int NT = N / 128;
  constexpr int NKT = K / 32;
  __shared__ __attribute__((aligned(16))) char smem[32768];  // 2x8KB + bounce

  const int tid = threadIdx.x;
  const int lane = tid & 63;
  const int w = tid >> 6;             // 0..3
  const int wr = w >> 1, wc = w & 1;  // wave tile 64x64

  // T1: XCD-aware bijective swizzle (grid % 8 == 0 by construction)
  const int cpx = gridDim.x >> 3;
  const int bid = (blockIdx.x & 7) * cpx + (blockIdx.x >> 3);
  const int tm = bid / NT, tn = bid - tm * NT;
  const size_t am0 = (size_t)tm * 128;
  const int bn0 = tn * 128;

  // A staging: thread stages segs tid (rows 0..63) and tid+256 (rows 64..127)
  const int r0 = tid >> 2, q0 = tid & 3;
  const __hip_bfloat16* aP0 = A + (am0 + r0) * K + q0 * 8;
  const __hip_bfloat16* aP1 = aP0 + (size_t)64 * K;
  const int wb = w * 1024;  // wave-uniform quarter offset

  // A-fragment geometry: row = wr*64 + m*16 + fr; byte = row*64 + kg*16
  const int fr = lane & 15;
  const int kb = (lane >> 4) * 16;
  const int abase = (wr * 64 + fr) * 64 + kb;  // + slot + m*1024

  // B packed stream: n-group g = tn*8 + wc*4 + n; frag = (g*NKT+t)*1024+lane*16
  const char* bBase = Bp + ((size_t)(tn * 8 + wc * 4) * NKT) * 1024 + lane * 16;

#define STAGE_A(so, kt)                                       \
  do {                                                        \
    load_lds16(aP0 + (kt) * 32, smem + (so) + wb);            \
    load_lds16(aP1 + (kt) * 32, smem + (so) + 4096 + wb);     \
  } while (0)

  f32x4 acc[4][4] = {};
  bf16x8 bf[4], bfn[4];

  // prologue: A tile0 -> slot0; B frags t=0
  STAGE_A(0, 0);
#pragma unroll
  for (int n = 0; n < 4; ++n)
    bf[n] = *(const bf16x8*)(bBase + ((size_t)n * NKT) * 1024);
  __syncthreads();

  for (int t = 0; t < NKT; ++t) {
    const int d = (t & 1) * 8192, dn = 8192 - d;
    // issue next tile's A-stage and B-prefetch FIRST (latency hidden by
    // this step's ds_read+MFMA; drained by the end-of-step barrier)
    if (t + 1 < NKT) {
      STAGE_A(dn, t + 1);
#pragma unroll
      for (int n = 0; n < 4; ++n)
        bfn[n] = *(const bf16x8*)(bBase + ((size_t)n * NKT + t + 1) * 1024);
    }

    bf16x8 af[4];
#pragma unroll
    for (int m = 0; m < 4; ++m)
      af[m] = *(const bf16x8*)(smem + d + abase + m * 1024);
#pragma unroll
    for (int m = 0; m < 4; ++m)
#pragma unroll
      for (int n = 0; n < 4; ++n)
        acc[m][n] = __builtin_amdgcn_mfma_f32_16x16x32_bf16(af[m], bf[n],
                                                            acc[m][n], 0, 0, 0);
    if (t + 1 < NKT) {
#pragma unroll
      for (int n = 0; n < 4; ++n) bf[n] = bfn[n];
    }
    __syncthreads();  // drains A-stage + bfn; seals slot d
  }
#undef STAGE_A

  // ---- epilogue via 32KB LDS bounce (R7/R12/R15-verified) ----
  // C/D map: col = lane&15, row = (lane>>4)*4 + j  [m89/m91-verified]
  const int cr = (lane >> 4) * 4;
  const int cc = lane & 15;
  char* smb = smem;

  if constexpr (GELU) {
    // bf16 out: 128x128 bf16 = exactly 32KB
    __hip_bfloat16* ot = (__hip_bfloat16*)smb;
#pragma unroll
    for (int n = 0; n < 4; ++n) {
      const int col = wc * 64 + n * 16 + cc;
      const float bv = bias[bn0 + col];
#pragma unroll
      for (int m = 0; m < 4; ++m) {
        const int row = wr * 64 + m * 16 + cr;
#pragma unroll
        for (int j = 0; j < 4; ++j)
          ot[(row + j) * 128 + col] =
              __float2bfloat16(gelu_tanh(acc[m][n][j] + bv));
      }
    }
    __syncthreads();
#pragma unroll
    for (int it = 0; it < 8; ++it) {
      const int seg = it * 256 + tid;  // 2048 x 16B = 32KB
      const int row = seg >> 4, cs = seg & 15;
      const uint4 v = *(const uint4*)(smb + seg * 16);
      *(uint4*)&zout[(am0 + row) * N + bn0 + cs * 8] = v;
    }
  } else {
    // fp32 RMW out: 2 passes of 64 rows (64x128 f32 = 32KB)
    float* ot = (float*)smb;
#pragma unroll
    for (int p = 0; p < 2; ++p) {
      if (p) __syncthreads();
      if (wr == p) {
#pragma unroll
        for (int n = 0; n < 4; ++n) {
          const int col = wc * 64 + n * 16 + cc;
          const float bv = bias[bn0 + col];
#pragma unroll
          for (int m = 0; m < 4; ++m) {
            const int rl = m * 16 + cr;
#pragma unroll
            for (int j = 0; j < 4; ++j)
              ot[(rl + j) * 128 + col] = acc[m][n][j] + bv;
          }
        }
      }
      __syncthreads();
#pragma unroll
      for (int it = 0; it < 8; ++it) {
        const int seg = it * 256 + tid;  // 2048 x 16B = 32KB
        const int row = seg >> 5, cs = seg & 31;
        const float4 lv = *(const float4*)(smb + seg * 16);
        float* gp = &fout[(am0 + p * 64 + row) * N + bn0 + cs * 4];
        float4 o = *(const float4*)gp;
        o.x += lv.x;
        o.y += lv.y;
        o.z += lv.z;
        o.w += lv.w;
        *(float4*)gp = o;
      }
    }
  }
}

extern "C" void kernel_launch(void* const* d_in, const int* in_sizes, int n_in,
                              void* d_out, int out_size, void* d_ws,
                              size_t ws_size, hipStream_t stream) {
  const float* x = (const float*)d_in[0];
  const float* n1g = (const float*)d_in[1];
  const float* n1b = (const float*)d_in[2];
  const float* wsp = (const float*)d_in[3];
  const float* n2g = (const float*)d_in[4];
  const float* n2b = (const float*)d_in[5];
  const float* w1 = (const float*)d_in[6];
  const float* b1 = (const float*)d_in[7];
  const float* w2 = (const float*)d_in[8];
  const float* b2 = (const float*)d_in[9];
  float* out = (float*)d_out;

  // ws (bf16): y[M*512] row-major | z[M*2048] row-major | w1p | w2p (packed)
  __hip_bfloat16* ybuf = (__hip_bfloat16*)d_ws;
  __hip_bfloat16* zbuf = ybuf + (size_t)MROWS * CDIM;
  __hip_bfloat16* w1p = zbuf + (size_t)MROWS * HID;
  __hip_bfloat16* w2p = w1p + (size_t)CDIM * HID;

  cvt_pack<CDIM, HID><<<512, 256, 0, stream>>>(w1, w1p);  // w1[512][2048]
  cvt_pack<HID, CDIM><<<512, 256, 0, stream>>>(w2, w2p);  // w2[2048][512]
  fused_pre<<<2048, 256, 0, stream>>>(x, n1g, n1b, wsp, n2g, n2b, out, ybuf);
  // grids: 784*16 = 12544 and 784*4 = 3136, both % 8 == 0
  gemmbs<CDIM, HID, true><<<(MROWS / 128) * (HID / 128), 256, 0, stream>>>(
      ybuf, (const char*)w1p, b1, zbuf, nullptr);
  gemmbs<HID, CDIM, false><<<(MROWS / 128) * (CDIM / 128), 256, 0, stream>>>(
      zbuf, (const char*)w2p, b2, nullptr, out);
}

// Round 18
// 879.025 us; speedup vs baseline: 1.5407x; 1.0018x over previous
//
#include <hip/hip_runtime.h>
#include <hip/hip_bf16.h>

// SwinMLP block, fp32 in/out, bf16 MFMA internals.
//   1) cvt_pack: w1/w2 -> MFMA-fragment-packed bf16 (R16-proven format)
//   2) fused_pre: LN1 + spatial mix + residual -> x2 (d_out); LN2 -> y (bf16)
//   3) gemmbk<512,2048,GELU>: z = gelu(y @ w1 + b1)
//   4) gemmbk<2048,512,RES>:  d_out = x2 + z @ w2 + b2
//
// R12->R17 series: per-CU time per 128²xBK32 K-step invariant ~1130cy across
// drain/ring/dbuf/B-stream/occupancy variants while every pipe meter moves
// (Mfma 24%, VALU 10->51%, LDS traffic halved, HBM 18%). Conclusion: the
// PER-STEP FIXED COST (barrier cadence + ds_read->MFMA latency chain) is the
// wall, not any pipe. R18 (this): BK=64 per barrier interval - two 32-k
// slabs per step; 32 MFMA + 4 stage-loads + 8 A-frag reads + ONE barrier.
// Steps halve (gemm1 8, gemm2 32) -> fixed cost amortizes. B streamed as
// R17 (h0 prefetched prior step; h1 loaded at step top, covered by h0 MFMA).

typedef __bf16 bf16x8 __attribute__((ext_vector_type(8)));
typedef float f32x4 __attribute__((ext_vector_type(4)));

constexpr int CDIM = 512;
constexpr int HID = 2048;
constexpr int MROWS = 32 * 3136;  // 100352 = 784 * 128
constexpr float LN_EPS = 1e-5f;

static __device__ __forceinline__ float gelu_tanh(float x) {
  const float u = 0.7978845608028654f * fmaf(0.044715f * x * x, x, x);
  const float e = __expf(2.0f * u);
  return 0.5f * x * (2.0f - 2.0f / (e + 1.0f));
}

static __device__ __forceinline__ void load_lds16(const void* g, void* l) {
  // 16B/lane; LDS dest = wave-uniform base + lane*16 (linear)
  __builtin_amdgcn_global_load_lds((__attribute__((address_space(1))) void*)g,
                                   (__attribute__((address_space(3))) void*)l,
                                   16, 0, 0);
}

// ---- pack fp32 w[KD][ND] -> bf16 packed fragments (R16-proven) ----
// Block o = (g*NKT + t)*64 + l (16B): n = g*16+(l&15), k = t*32+(l>>4)*8+j.
template <int KD, int ND>
__global__ __launch_bounds__(256) void cvt_pack(const float* __restrict__ src,
                                                __hip_bfloat16* __restrict__ dst) {
  constexpr int NKT = KD / 32;
  const int o = blockIdx.x * 256 + threadIdx.x;
  const int l = o & 63;
  const int gt = o >> 6;
  const int t = gt & (NKT - 1), g = gt / NKT;
  const int n = g * 16 + (l & 15);
  const int k0 = t * 32 + (l >> 4) * 8;
  __hip_bfloat16 v[8];
#pragma unroll
  for (int j = 0; j < 8; ++j)
    v[j] = __float2bfloat16(src[(size_t)(k0 + j) * ND + n]);
  *(uint4*)(dst + (size_t)o * 8) = *(const uint4*)v;
}

// -------- fused LN1 + spatial mix + residual + LN2, 2 rows / iteration ------
__global__ __launch_bounds__(256) void fused_pre(
    const float* __restrict__ x, const float* __restrict__ g1,
    const float* __restrict__ b1, const float* __restrict__ wsp,
    const float* __restrict__ g2, const float* __restrict__ b2,
    float* __restrict__ x2out, __hip_bfloat16* __restrict__ yout) {
  __shared__ float lnbuf[2][CDIM];
  __shared__ float red[16];

  const int t = threadIdx.x;
  const int lane = t & 63;
  const int w = t >> 6;
  const int c0 = 2 * t;
  const int hd = c0 >> 5, e0 = c0 & 31;

  float wc0[32], wc1[32];
#pragma unroll
  for (int d = 0; d < 32; ++d) {
    const float2 wv = *(const float2*)&wsp[(hd * 32 + d) * 32 + e0];
    wc0[d] = wv.x;
    wc1[d] = wv.y;
  }
  const float2 g1v = *(const float2*)&g1[c0];
  const float2 b1v = *(const float2*)&b1[c0];
  const float2 g2v = *(const float2*)&g2[c0];
  const float2 b2v = *(const float2*)&b2[c0];

  for (int rp = blockIdx.x; rp < MROWS / 2; rp += gridDim.x) {
    const size_t ra = (size_t)rp * 2, rb = ra + 1;
    const float2 xa = *(const float2*)&x[ra * CDIM + c0];
    const float2 xb = *(const float2*)&x[rb * CDIM + c0];

    float sa = xa.x + xa.y, qa = xa.x * xa.x + xa.y * xa.y;
    float sb = xb.x + xb.y, qb = xb.x * xb.x + xb.y * xb.y;
#pragma unroll
    for (int off = 32; off; off >>= 1) {
      sa += __shfl_down(sa, off);
      qa += __shfl_down(qa, off);
      sb += __shfl_down(sb, off);
      qb += __shfl_down(qb, off);
    }
    if (lane == 0) {
      red[w * 4 + 0] = sa;
      red[w * 4 + 1] = qa;
      red[w * 4 + 2] = sb;
      red[w * 4 + 3] = qb;
    }
    __syncthreads();  // B1
    sa = red[0] + red[4] + red[8] + red[12];
    qa = red[1] + red[5] + red[9] + red[13];
    sb = red[2] + red[6] + red[10] + red[14];
    qb = red[3] + red[7] + red[11] + red[15];
    float mua = sa * (1.0f / CDIM), mub = sb * (1.0f / CDIM);
    float rsa = rsqrtf(qa * (1.0f / CDIM) - mua * mua + LN_EPS);
    float rsb = rsqrtf(qb * (1.0f / CDIM) - mub * mub + LN_EPS);
    lnbuf[0][c0] = (xa.x - mua) * rsa * g1v.x + b1v.x;
    lnbuf[0][c0 + 1] = (xa.y - mua) * rsa * g1v.y + b1v.y;
    lnbuf[1][c0] = (xb.x - mub) * rsb * g1v.x + b1v.x;
    lnbuf[1][c0 + 1] = (xb.y - mub) * rsb * g1v.y + b1v.y;
    __syncthreads();  // B2

    float ha0 = 0.f, ha1 = 0.f, hb0 = 0.f, hb1 = 0.f;
#pragma unroll
    for (int d = 0; d < 32; ++d) {
      const float la = lnbuf[0][hd * 32 + d];
      const float lb = lnbuf[1][hd * 32 + d];
      ha0 = fmaf(la, wc0[d], ha0);
      ha1 = fmaf(la, wc1[d], ha1);
      hb0 = fmaf(lb, wc0[d], hb0);
      hb1 = fmaf(lb, wc1[d], hb1);
    }
    const float a0 = xa.x + ha0, a1 = xa.y + ha1;
    const float b0 = xb.x + hb0, b1r = xb.y + hb1;
    float2 av;
    av.x = a0;
    av.y = a1;
    *(float2*)&x2out[ra * CDIM + c0] = av;
    av.x = b0;
    av.y = b1r;
    *(float2*)&x2out[rb * CDIM + c0] = av;

    sa = a0 + a1;
    qa = a0 * a0 + a1 * a1;
    sb = b0 + b1r;
    qb = b0 * b0 + b1r * b1r;
#pragma unroll
    for (int off = 32; off; off >>= 1) {
      sa += __shfl_down(sa, off);
      qa += __shfl_down(qa, off);
      sb += __shfl_down(sb, off);
      qb += __shfl_down(qb, off);
    }
    if (lane == 0) {
      red[w * 4 + 0] = sa;
      red[w * 4 + 1] = qa;
      red[w * 4 + 2] = sb;
      red[w * 4 + 3] = qb;
    }
    __syncthreads();  // B3
    sa = red[0] + red[4] + red[8] + red[12];
    qa = red[1] + red[5] + red[9] + red[13];
    sb = red[2] + red[6] + red[10] + red[14];
    qb = red[3] + red[7] + red[11] + red[15];
    mua = sa * (1.0f / CDIM);
    mub = sb * (1.0f / CDIM);
    rsa = rsqrtf(qa * (1.0f / CDIM) - mua * mua + LN_EPS);
    rsb = rsqrtf(qb * (1.0f / CDIM) - mub * mub + LN_EPS);
    __hip_bfloat162 yv;
    yv.x = __float2bfloat16((a0 - mua) * rsa * g2v.x + b2v.x);
    yv.y = __float2bfloat16((a1 - mua) * rsa * g2v.y + b2v.y);
    *(__hip_bfloat162*)&yout[ra * CDIM + c0] = yv;
    yv.x = __float2bfloat16((b0 - mub) * rsb * g2v.x + b2v.x);
    yv.y = __float2bfloat16((b1r - mub) * rsb * g2v.y + b2v.y);
    *(__hip_bfloat162*)&yout[rb * CDIM + c0] = yv;
    __syncthreads();  // B4
  }
}

// ---- 128x128 tile, 4 waves, BK=64/step: A LDS-dbuf, B global-streamed ----
// C(MxN) = A(MxK) * Bpacked.  LDS = 2 A-slots x 16KB (half h at +h*8192).
// Per step t (slot d): issue STAGE_A(t+1) + prefetch bfn(h0 of t+1); load
// bh1 (h1 of t); ds_read A-h0 + 16 MFMA; ds_read A-h1 + 16 MFMA (bh1's L1
// latency covered by h0 compute); bf=bfn; ONE __syncthreads.
template <int K, int N, bool GELU>
__global__ __launch_bounds__(256, 3) void gemmbk(
    const __hip_bfloat16* __restrict__ A, const char* __restrict__ Bp,
    const float* __restrict__ bias, __hip_bfloat16* __restrict__ zout,
    float* __restrict__ fout) {
  constexpr int NT = N / 128;
  constexpr int NKT = K / 32;   // packed-B k-tile count
  constexpr int NST = K / 64;   // barrier steps
  __shared__ __attribute__((aligned(16))) char smem[32768];  // 2 x 16KB

  const int tid = threadIdx.x;
  const int lane = tid & 63;
  const int w = tid >> 6;             // 0..3
  const int wr = w >> 1, wc = w & 1;  // wave tile 64x64

  // T1: XCD-aware bijective swizzle (grid % 8 == 0 by construction)
  const int cpx = gridDim.x >> 3;
  const int bid = (blockIdx.x & 7) * cpx + (blockIdx.x >> 3);
  const int tm = bid / NT, tn = bid - tm * NT;
  const size_t am0 = (size_t)tm * 128;
  const int bn0 = tn * 128;

  // A staging: thread stages rows r0 (0..63) and r0+64 per 32-k slab
  const int r0 = tid >> 2, q0 = tid & 3;
  const __hip_bfloat16* aP0 = A + (am0 + r0) * K + q0 * 8;
  const __hip_bfloat16* aP1 = aP0 + (size_t)64 * K;
  const int wb = w * 1024;  // wave-uniform quarter offset

  // A-fragment geometry: byte = slot + h*8192 + (wr*64+m*16+fr)*64 + kg*16
  const int fr = lane & 15;
  const int kb = (lane >> 4) * 16;
  const int abase = (wr * 64 + fr) * 64 + kb;

  // B packed stream: n-group g = tn*8 + wc*4 + n; frag (g*NKT + kt)*1024
  const char* bBase = Bp + ((size_t)(tn * 8 + wc * 4) * NKT) * 1024 + lane * 16;

#define STAGE_A(so, t1)                                            \
  do {                                                             \
    load_lds16(aP0 + (t1) * 64, smem + (so) + wb);                 \
    load_lds16(aP1 + (t1) * 64, smem + (so) + 4096 + wb);          \
    load_lds16(aP0 + (t1) * 64 + 32, smem + (so) + 8192 + wb);     \
    load_lds16(aP1 + (t1) * 64 + 32, smem + (so) + 12288 + wb);    \
  } while (0)

  f32x4 acc[4][4] = {};
  bf16x8 bf[4], bfn[4], bh1[4], af[4];

  // prologue: A step0 -> slot0; B h0-frags of step0
  STAGE_A(0, 0);
#pragma unroll
  for (int n = 0; n < 4; ++n)
    bf[n] = *(const bf16x8*)(bBase + (n * NKT) * 1024);
  __syncthreads();

  for (int t = 0; t < NST; ++t) {
    const int d = (t & 1) * 16384, dn = 16384 - d;
    // issue next step's A-stage + B-h0 prefetch FIRST
    if (t + 1 < NST) {
      STAGE_A(dn, t + 1);
#pragma unroll
      for (int n = 0; n < 4; ++n)
        bfn[n] = *(const bf16x8*)(bBase + (n * NKT + 2 * (t + 1)) * 1024);
    }
    // this step's B-h1 frags (L1-hot; latency covered by h0 compute below)
#pragma unroll
    for (int n = 0; n < 4; ++n)
      bh1[n] = *(const bf16x8*)(bBase + (n * NKT + 2 * t + 1) * 1024);

    // slab h0
#pragma unroll
    for (int m = 0; m < 4; ++m)
      af[m] = *(const bf16x8*)(smem + d + abase + m * 1024);
#pragma unroll
    for (int m = 0; m < 4; ++m)
#pragma unroll
      for (int n = 0; n < 4; ++n)
        acc[m][n] = __builtin_amdgcn_mfma_f32_16x16x32_bf16(af[m], bf[n],
                                                            acc[m][n], 0, 0, 0);
    // slab h1
#pragma unroll
    for (int m = 0; m < 4; ++m)
      af[m] = *(const bf16x8*)(smem + d + 8192 + abase + m * 1024);
#pragma unroll
    for (int m = 0; m < 4; ++m)
#pragma unroll
      for (int n = 0; n < 4; ++n)
        acc[m][n] = __builtin_amdgcn_mfma_f32_16x16x32_bf16(af[m], bh1[n],
                                                            acc[m][n], 0, 0, 0);
    if (t + 1 < NST) {
#pragma unroll
      for (int n = 0; n < 4; ++n) bf[n] = bfn[n];
    }
    __syncthreads();  // drains A-stage + B prefetches; seals slot d
  }
#undef STAGE_A

  // ---- epilogue via 32KB LDS bounce (R7/R12/R15-verified) ----
  // C/D map: col = lane&15, row = (lane>>4)*4 + j  [m89/m91-verified]
  const int cr = (lane >> 4) * 4;
  const int cc = lane & 15;
  char* smb = smem;

  if constexpr (GELU) {
    // bf16 out: 128x128 bf16 = exactly 32KB
    __hip_bfloat16* ot = (__hip_bfloat16*)smb;
#pragma unroll
    for (int n = 0; n < 4; ++n) {
      const int col = wc * 64 + n * 16 + cc;
      const float bv = bias[bn0 + col];
#pragma unroll
      for (int m = 0; m < 4; ++m) {
        const int row = wr * 64 + m * 16 + cr;
#pragma unroll
        for (int j = 0; j < 4; ++j)
          ot[(row + j) * 128 + col] =
              __float2bfloat16(gelu_tanh(acc[m][n][j] + bv));
      }
    }
    __syncthreads();
#pragma unroll
    for (int it = 0; it < 8; ++it) {
      const int seg = it * 256 + tid;  // 2048 x 16B = 32KB
      const int row = seg >> 4, cs = seg & 15;
      const uint4 v = *(const uint4*)(smb + seg * 16);
      *(uint4*)&zout[(am0 + row) * N + bn0 + cs * 8] = v;
    }
  } else {
    // fp32 RMW out: 2 passes of 64 rows (64x128 f32 = 32KB)
    float* ot = (float*)smb;
#pragma unroll
    for (int p = 0; p < 2; ++p) {
      if (p) __syncthreads();
      if (wr == p) {
#pragma unroll
        for (int n = 0; n < 4; ++n) {
          const int col = wc * 64 + n * 16 + cc;
          const float bv = bias[bn0 + col];
#pragma unroll
          for (int m = 0; m < 4; ++m) {
            const int rl = m * 16 + cr;
#pragma unroll
            for (int j = 0; j < 4; ++j)
              ot[(rl + j) * 128 + col] = acc[m][n][j] + bv;
          }
        }
      }
      __syncthreads();
#pragma unroll
      for (int it = 0; it < 8; ++it) {
        const int seg = it * 256 + tid;  // 2048 x 16B = 32KB
        const int row = seg >> 5, cs = seg & 31;
        const float4 lv = *(const float4*)(smb + seg * 16);
        float* gp = &fout[(am0 + p * 64 + row) * N + bn0 + cs * 4];
        float4 o = *(const float4*)gp;
        o.x += lv.x;
        o.y += lv.y;
        o.z += lv.z;
        o.w += lv.w;
        *(float4*)gp = o;
      }
    }
  }
}

extern "C" void kernel_launch(void* const* d_in, const int* in_sizes, int n_in,
                              void* d_out, int out_size, void* d_ws,
                              size_t ws_size, hipStream_t stream) {
  const float* x = (const float*)d_in[0];
  const float* n1g = (const float*)d_in[1];
  const float* n1b = (const float*)d_in[2];
  const float* wsp = (const float*)d_in[3];
  const float* n2g = (const float*)d_in[4];
  const float* n2b = (const float*)d_in[5];
  const float* w1 = (const float*)d_in[6];
  const float* b1 = (const float*)d_in[7];
  const float* w2 = (const float*)d_in[8];
  const float* b2 = (const float*)d_in[9];
  float* out = (float*)d_out;

  // ws (bf16): y[M*512] row-major | z[M*2048] row-major | w1p | w2p (packed)
  __hip_bfloat16* ybuf = (__hip_bfloat16*)d_ws;
  __hip_bfloat16* zbuf = ybuf + (size_t)MROWS * CDIM;
  __hip_bfloat16* w1p = zbuf + (size_t)MROWS * HID;
  __hip_bfloat16* w2p = w1p + (size_t)CDIM * HID;

  cvt_pack<CDIM, HID><<<512, 256, 0, stream>>>(w1, w1p);  // w1[512][2048]
  cvt_pack<HID, CDIM><<<512, 256, 0, stream>>>(w2, w2p);  // w2[2048][512]
  fused_pre<<<2048, 256, 0, stream>>>(x, n1g, n1b, wsp, n2g, n2b, out, ybuf);
  // grids: 784*16 = 12544 and 784*4 = 3136, both % 8 == 0
  gemmbk<CDIM, HID, true><<<(MROWS / 128) * (HID / 128), 256, 0, stream>>>(
      ybuf, (const char*)w1p, b1, zbuf, nullptr);
  gemmbk<HID, CDIM, false><<<(MROWS / 128) * (CDIM / 128), 256, 0, stream>>>(
      zbuf, (const char*)w2p, b2, nullptr, out);
}

// Round 19
// 863.285 us; speedup vs baseline: 1.5688x; 1.0182x over previous
//
#include <hip/hip_runtime.h>
#include <hip/hip_bf16.h>

// SwinMLP block, fp32 in/out, bf16 MFMA internals.
//   1) cvt_pack32: w1/w2 -> bf16 packed 32x32-MFMA B-fragments
//   2) fused_pre: LN1 + spatial mix + residual -> x2 (d_out); LN2 -> y (bf16)
//   3) gemm32<512,2048,GELU>: z = gelu(y @ w1 + b1)
//   4) gemm32<2048,512,RES>:  d_out = x2 + z @ w2 + b2
//
// R12-R18: EIGHT structure variants invariant at ~370us/gemm (567 TF) while
// all pipe meters move freely. Last untested pipe lever: the MFMA instruction
// stream. R19 (this): 32x32x16 MFMA on the R17 base - halves instruction
// count (8/step vs 16), +15% instruction ceiling (2382 vs 2075 TF), 4-wide
// ILP chain depth 2. acc = 4 x f32x16 = 64 AGPR (same). A-operand mapping
// row=lane&31, k=(lane>>5)*8+j (pattern-consistent with verified 16x16);
// C/D col=lane&31, row=(reg&3)+8*(reg>>2)+4*(lane>>5) [m74/m101-verified].

typedef __bf16 bf16x8 __attribute__((ext_vector_type(8)));
typedef float f32x16 __attribute__((ext_vector_type(16)));

constexpr int CDIM = 512;
constexpr int HID = 2048;
constexpr int MROWS = 32 * 3136;  // 100352 = 784 * 128
constexpr float LN_EPS = 1e-5f;

static __device__ __forceinline__ float gelu_tanh(float x) {
  const float u = 0.7978845608028654f * fmaf(0.044715f * x * x, x, x);
  const float e = __expf(2.0f * u);
  return 0.5f * x * (2.0f - 2.0f / (e + 1.0f));
}

static __device__ __forceinline__ void load_lds16(const void* g, void* l) {
  // 16B/lane; LDS dest = wave-uniform base + lane*16 (linear)
  __builtin_amdgcn_global_load_lds((__attribute__((address_space(1))) void*)g,
                                   (__attribute__((address_space(3))) void*)l,
                                   16, 0, 0);
}

// ---- pack fp32 w[KD][ND] -> bf16 32x32-frag blocks ----
// Block o = (g*NKT2 + t)*64 + l (16B each): n = g*32 + (l&31),
// k = t*16 + (l>>5)*8 + j, j = 0..7.
template <int KD, int ND>
__global__ __launch_bounds__(256) void cvt_pack32(
    const float* __restrict__ src, __hip_bfloat16* __restrict__ dst) {
  constexpr int NKT2 = KD / 16;
  const int o = blockIdx.x * 256 + threadIdx.x;
  const int l = o & 63;
  const int gt = o >> 6;
  const int t = gt & (NKT2 - 1), g = gt / NKT2;
  const int n = g * 32 + (l & 31);
  const int k0 = t * 16 + (l >> 5) * 8;
  __hip_bfloat16 v[8];
#pragma unroll
  for (int j = 0; j < 8; ++j)
    v[j] = __float2bfloat16(src[(size_t)(k0 + j) * ND + n]);
  *(uint4*)(dst + (size_t)o * 8) = *(const uint4*)v;
}

// -------- fused LN1 + spatial mix + residual + LN2, 2 rows / iteration ------
__global__ __launch_bounds__(256) void fused_pre(
    const float* __restrict__ x, const float* __restrict__ g1,
    const float* __restrict__ b1, const float* __restrict__ wsp,
    const float* __restrict__ g2, const float* __restrict__ b2,
    float* __restrict__ x2out, __hip_bfloat16* __restrict__ yout) {
  __shared__ float lnbuf[2][CDIM];
  __shared__ float red[16];

  const int t = threadIdx.x;
  const int lane = t & 63;
  const int w = t >> 6;
  const int c0 = 2 * t;
  const int hd = c0 >> 5, e0 = c0 & 31;

  float wc0[32], wc1[32];
#pragma unroll
  for (int d = 0; d < 32; ++d) {
    const float2 wv = *(const float2*)&wsp[(hd * 32 + d) * 32 + e0];
    wc0[d] = wv.x;
    wc1[d] = wv.y;
  }
  const float2 g1v = *(const float2*)&g1[c0];
  const float2 b1v = *(const float2*)&b1[c0];
  const float2 g2v = *(const float2*)&g2[c0];
  const float2 b2v = *(const float2*)&b2[c0];

  for (int rp = blockIdx.x; rp < MROWS / 2; rp += gridDim.x) {
    const size_t ra = (size_t)rp * 2, rb = ra + 1;
    const float2 xa = *(const float2*)&x[ra * CDIM + c0];
    const float2 xb = *(const float2*)&x[rb * CDIM + c0];

    float sa = xa.x + xa.y, qa = xa.x * xa.x + xa.y * xa.y;
    float sb = xb.x + xb.y, qb = xb.x * xb.x + xb.y * xb.y;
#pragma unroll
    for (int off = 32; off; off >>= 1) {
      sa += __shfl_down(sa, off);
      qa += __shfl_down(qa, off);
      sb += __shfl_down(sb, off);
      qb += __shfl_down(qb, off);
    }
    if (lane == 0) {
      red[w * 4 + 0] = sa;
      red[w * 4 + 1] = qa;
      red[w * 4 + 2] = sb;
      red[w * 4 + 3] = qb;
    }
    __syncthreads();  // B1
    sa = red[0] + red[4] + red[8] + red[12];
    qa = red[1] + red[5] + red[9] + red[13];
    sb = red[2] + red[6] + red[10] + red[14];
    qb = red[3] + red[7] + red[11] + red[15];
    float mua = sa * (1.0f / CDIM), mub = sb * (1.0f / CDIM);
    float rsa = rsqrtf(qa * (1.0f / CDIM) - mua * mua + LN_EPS);
    float rsb = rsqrtf(qb * (1.0f / CDIM) - mub * mub + LN_EPS);
    lnbuf[0][c0] = (xa.x - mua) * rsa * g1v.x + b1v.x;
    lnbuf[0][c0 + 1] = (xa.y - mua) * rsa * g1v.y + b1v.y;
    lnbuf[1][c0] = (xb.x - mub) * rsb * g1v.x + b1v.x;
    lnbuf[1][c0 + 1] = (xb.y - mub) * rsb * g1v.y + b1v.y;
    __syncthreads();  // B2

    float ha0 = 0.f, ha1 = 0.f, hb0 = 0.f, hb1 = 0.f;
#pragma unroll
    for (int d = 0; d < 32; ++d) {
      const float la = lnbuf[0][hd * 32 + d];
      const float lb = lnbuf[1][hd * 32 + d];
      ha0 = fmaf(la, wc0[d], ha0);
      ha1 = fmaf(la, wc1[d], ha1);
      hb0 = fmaf(lb, wc0[d], hb0);
      hb1 = fmaf(lb, wc1[d], hb1);
    }
    const float a0 = xa.x + ha0, a1 = xa.y + ha1;
    const float b0 = xb.x + hb0, b1r = xb.y + hb1;
    float2 av;
    av.x = a0;
    av.y = a1;
    *(float2*)&x2out[ra * CDIM + c0] = av;
    av.x = b0;
    av.y = b1r;
    *(float2*)&x2out[rb * CDIM + c0] = av;

    sa = a0 + a1;
    qa = a0 * a0 + a1 * a1;
    sb = b0 + b1r;
    qb = b0 * b0 + b1r * b1r;
#pragma unroll
    for (int off = 32; off; off >>= 1) {
      sa += __shfl_down(sa, off);
      qa += __shfl_down(qa, off);
      sb += __shfl_down(sb, off);
      qb += __shfl_down(qb, off);
    }
    if (lane == 0) {
      red[w * 4 + 0] = sa;
      red[w * 4 + 1] = qa;
      red[w * 4 + 2] = sb;
      red[w * 4 + 3] = qb;
    }
    __syncthreads();  // B3
    sa = red[0] + red[4] + red[8] + red[12];
    qa = red[1] + red[5] + red[9] + red[13];
    sb = red[2] + red[6] + red[10] + red[14];
    qb = red[3] + red[7] + red[11] + red[15];
    mua = sa * (1.0f / CDIM);
    mub = sb * (1.0f / CDIM);
    rsa = rsqrtf(qa * (1.0f / CDIM) - mua * mua + LN_EPS);
    rsb = rsqrtf(qb * (1.0f / CDIM) - mub * mub + LN_EPS);
    __hip_bfloat162 yv;
    yv.x = __float2bfloat16((a0 - mua) * rsa * g2v.x + b2v.x);
    yv.y = __float2bfloat16((a1 - mua) * rsa * g2v.y + b2v.y);
    *(__hip_bfloat162*)&yout[ra * CDIM + c0] = yv;
    yv.x = __float2bfloat16((b0 - mub) * rsb * g2v.x + b2v.x);
    yv.y = __float2bfloat16((b1r - mub) * rsb * g2v.y + b2v.y);
    *(__hip_bfloat162*)&yout[rb * CDIM + c0] = yv;
    __syncthreads();  // B4
  }
}

// ---- 128x128 tile, 4 waves, BK=32, 32x32x16 MFMA; A LDS-dbuf, B streamed ---
// C(MxN) = A(MxK) * Bpacked.  Wave tile 64x64 = 2x2 frags of 32x32.
// Per step t (slot d=t&1): STAGE_A(t+1->d^1) + B-prefetch(t+1) FIRST;
// ds_read A-frags (row=lane&31, k-half=lane>>5); 8 MFMA; __syncthreads.
template <int K, int N, bool GELU>
__global__ __launch_bounds__(256, 3) void gemm32(
    const __hip_bfloat16* __restrict__ A, const char* __restrict__ Bp,
    const float* __restrict__ bias, __hip_bfloat16* __restrict__ zout,
    float* __restrict__ fout) {
  constexpr int NT = N / 128;
  constexpr int NKT2 = K / 16;  // packed-B 16-k tile count
  constexpr int NST = K / 32;   // barrier steps
  __shared__ __attribute__((aligned(16))) char smem[32768];  // 2x8KB + bounce

  const int tid = threadIdx.x;
  const int lane = tid & 63;
  const int w = tid >> 6;             // 0..3
  const int wr = w >> 1, wc = w & 1;  // wave tile 64x64

  // T1: XCD-aware bijective swizzle (grid % 8 == 0 by construction)
  const int cpx = gridDim.x >> 3;
  const int bid = (blockIdx.x & 7) * cpx + (blockIdx.x >> 3);
  const int tm = bid / NT, tn = bid - tm * NT;
  const size_t am0 = (size_t)tm * 128;
  const int bn0 = tn * 128;

  // A staging (identical to R17): 8KB slab = 128 rows x 32 k bf16
  const int r0 = tid >> 2, q0 = tid & 3;
  const __hip_bfloat16* aP0 = A + (am0 + r0) * K + q0 * 8;
  const __hip_bfloat16* aP1 = aP0 + (size_t)64 * K;
  const int wb = w * 1024;  // wave-uniform quarter offset

  // A-frag geometry (32x32x16): row = wr*64 + mi*32 + (lane&31);
  // byte = row*64 + kh*32 + (lane>>5)*16
  const int arow = (lane & 31);
  const int akb = (lane >> 5) * 16;
  const int abase = (wr * 64 + arow) * 64 + akb;  // + slot + mi*2048 + kh*32

  // B packed stream: n-group g = tn*4 + wc*2 + ni; frag (g*NKT2 + t16)*1024
  const char* bBase =
      Bp + ((size_t)(tn * 4 + wc * 2) * NKT2) * 1024 + lane * 16;

#define STAGE_A(so, kt)                                       \
  do {                                                        \
    load_lds16(aP0 + (kt) * 32, smem + (so) + wb);            \
    load_lds16(aP1 + (kt) * 32, smem + (so) + 4096 + wb);     \
  } while (0)

  f32x16 acc[2][2] = {};
  bf16x8 bf[2][2], bfn[2][2], af[2][2];

  // prologue: A tile0 -> slot0; B frags of step 0 (t16 = 0,1)
  STAGE_A(0, 0);
#pragma unroll
  for (int ni = 0; ni < 2; ++ni)
#pragma unroll
    for (int kh = 0; kh < 2; ++kh)
      bf[ni][kh] = *(const bf16x8*)(bBase + ((size_t)ni * NKT2 + kh) * 1024);
  __syncthreads();

  for (int t = 0; t < NST; ++t) {
    const int d = (t & 1) * 8192, dn = 8192 - d;
    // issue next step's A-stage and B-prefetch FIRST
    if (t + 1 < NST) {
      STAGE_A(dn, t + 1);
#pragma unroll
      for (int ni = 0; ni < 2; ++ni)
#pragma unroll
        for (int kh = 0; kh < 2; ++kh)
          bfn[ni][kh] = *(const bf16x8*)(bBase +
                                         ((size_t)ni * NKT2 + 2 * (t + 1) + kh) *
                                             1024);
    }

#pragma unroll
    for (int mi = 0; mi < 2; ++mi)
#pragma unroll
      for (int kh = 0; kh < 2; ++kh)
        af[mi][kh] =
            *(const bf16x8*)(smem + d + abase + mi * 2048 + kh * 32);
#pragma unroll
    for (int kh = 0; kh < 2; ++kh)
#pragma unroll
      for (int mi = 0; mi < 2; ++mi)
#pragma unroll
        for (int ni = 0; ni < 2; ++ni)
          acc[mi][ni] = __builtin_amdgcn_mfma_f32_32x32x16_bf16(
              af[mi][kh], bf[ni][kh], acc[mi][ni], 0, 0, 0);
    if (t + 1 < NST) {
#pragma unroll
      for (int ni = 0; ni < 2; ++ni)
#pragma unroll
        for (int kh = 0; kh < 2; ++kh) bf[ni][kh] = bfn[ni][kh];
    }
    __syncthreads();  // drains A-stage + B prefetch; seals slot d
  }
#undef STAGE_A

  // ---- epilogue via 32KB LDS bounce ----
  // 32x32 C/D map: col = lane&31, row = (reg&3)+8*(reg>>2)+4*(lane>>5)
  // [m74/m101-verified]
  const int ccol = lane & 31;
  const int rbase = 4 * (lane >> 5);
  char* smb = smem;

  if constexpr (GELU) {
    __hip_bfloat16* ot = (__hip_bfloat16*)smb;
#pragma unroll
    for (int ni = 0; ni < 2; ++ni) {
      const int col = wc * 64 + ni * 32 + ccol;
      const float bv = bias[bn0 + col];
#pragma unroll
      for (int mi = 0; mi < 2; ++mi)
#pragma unroll
        for (int r = 0; r < 16; ++r) {
          const int row = wr * 64 + mi * 32 + (r & 3) + 8 * (r >> 2) + rbase;
          ot[row * 128 + col] =
              __float2bfloat16(gelu_tanh(acc[mi][ni][r] + bv));
        }
    }
    __syncthreads();
#pragma unroll
    for (int it = 0; it < 8; ++it) {
      const int seg = it * 256 + tid;  // 2048 x 16B = 32KB
      const int row = seg >> 4, cs = seg & 15;
      const uint4 v = *(const uint4*)(smb + seg * 16);
      *(uint4*)&zout[(am0 + row) * N + bn0 + cs * 8] = v;
    }
  } else {
    float* ot = (float*)smb;
#pragma unroll
    for (int p = 0; p < 2; ++p) {
      if (p) __syncthreads();
      if (wr == p) {
#pragma unroll
        for (int ni = 0; ni < 2; ++ni) {
          const int col = wc * 64 + ni * 32 + ccol;
          const float bv = bias[bn0 + col];
#pragma unroll
          for (int mi = 0; mi < 2; ++mi)
#pragma unroll
            for (int r = 0; r < 16; ++r) {
              const int rl = mi * 32 + (r & 3) + 8 * (r >> 2) + rbase;
              ot[rl * 128 + col] = acc[mi][ni][r] + bv;
            }
        }
      }
      __syncthreads();
#pragma unroll
      for (int it = 0; it < 8; ++it) {
        const int seg = it * 256 + tid;  // 2048 x 16B = 32KB
        const int row = seg >> 5, cs = seg & 31;
        const float4 lv = *(const float4*)(smb + seg * 16);
        float* gp = &fout[(am0 + p * 64 + row) * N + bn0 + cs * 4];
        float4 o = *(const float4*)gp;
        o.x += lv.x;
        o.y += lv.y;
        o.z += lv.z;
        o.w += lv.w;
        *(float4*)gp = o;
      }
    }
  }
}

extern "C" void kernel_launch(void* const* d_in, const int* in_sizes, int n_in,
                              void* d_out, int out_size, void* d_ws,
                              size_t ws_size, hipStream_t stream) {
  const float* x = (const float*)d_in[0];
  const float* n1g = (const float*)d_in[1];
  const float* n1b = (const float*)d_in[2];
  const float* wsp = (const float*)d_in[3];
  const float* n2g = (const float*)d_in[4];
  const float* n2b = (const float*)d_in[5];
  const float* w1 = (const float*)d_in[6];
  const float* b1 = (const float*)d_in[7];
  const float* w2 = (const float*)d_in[8];
  const float* b2 = (const float*)d_in[9];
  float* out = (float*)d_out;

  // ws (bf16): y[M*512] row-major | z[M*2048] row-major | w1p | w2p (packed32)
  __hip_bfloat16* ybuf = (__hip_bfloat16*)d_ws;
  __hip_bfloat16* zbuf = ybuf + (size_t)MROWS * CDIM;
  __hip_bfloat16* w1p = zbuf + (size_t)MROWS * HID;
  __hip_bfloat16* w2p = w1p + (size_t)CDIM * HID;

  cvt_pack32<CDIM, HID><<<512, 256, 0, stream>>>(w1, w1p);  // w1[512][2048]
  cvt_pack32<HID, CDIM><<<512, 256, 0, stream>>>(w2, w2p);  // w2[2048][512]
  fused_pre<<<2048, 256, 0, stream>>>(x, n1g, n1b, wsp, n2g, n2b, out, ybuf);
  // grids: 784*16 = 12544 and 784*4 = 3136, both % 8 == 0
  gemm32<CDIM, HID, true><<<(MROWS / 128) * (HID / 128), 256, 0, stream>>>(
      ybuf, (const char*)w1p, b1, zbuf, nullptr);
  gemm32<HID, CDIM, false><<<(MROWS / 128) * (CDIM / 128), 256, 0, stream>>>(
      zbuf, (const char*)w2p, b2, nullptr, out);
}